// Round 16
// baseline (104.614 us; speedup 1.0000x reference)
//
#include <hip/hip_runtime.h>
#include <math.h>

// Problem dims (fixed by setup_inputs)
#define HW   16384
#define BS   16
#define C    256
#define NQ   100
#define NQP  112          // padded nq (7 x 16)
#define Hh   128
#define Ww   128

// output layout offsets (floats)
#define SIM_OFF   3200                 // after proposal_for_loss [16,100,2]
#define PROPS_OFF (3200 + 26214400)    // after similarity [16,100,16384]

#define BM 256           // hw per block (2 grid rows)
#define BK 64            // k per step (2 MFMA sub-steps of K=32)
#define NBLK (HW / BM)   // 64 partials per row
#define NW   8           // waves per block (512 threads)

typedef _Float16 half8 __attribute__((ext_vector_type(8)));
typedef float f32x4 __attribute__((ext_vector_type(4)));

__device__ __forceinline__ void gll16(const void* gp, void* lp) {
    __builtin_amdgcn_global_load_lds((const __attribute__((address_space(1))) void*)gp,
                                     (__attribute__((address_space(3))) void*)lp, 16, 0, 0);
}

__device__ __forceinline__ half8 cvt8(const float4 a, const float4 b) {
    _Float16 h[8] = {(_Float16)a.x, (_Float16)a.y, (_Float16)a.z, (_Float16)a.w,
                     (_Float16)b.x, (_Float16)b.y, (_Float16)b.z, (_Float16)b.w};
    return *(half8*)h;
}

// ---------------- S pre-convert kernel ----------------
// S [nq, bs, c] fp32 -> Sh [bs][112][256] fp16 (rows >= NQ zero)
__global__ __launch_bounds__(256) void conv_S_kernel(const float* __restrict__ S,
                                                     _Float16* __restrict__ sh)
{
    int idx4 = blockIdx.x * 256 + threadIdx.x;
    int idx = idx4 * 4;
    if (idx >= BS * NQP * C) return;
    int b = idx / (NQP * C);
    int rem = idx - b * (NQP * C);
    int n = rem / C;
    int k = rem - n * C;
    float4 v = make_float4(0.f, 0.f, 0.f, 0.f);
    if (n < NQ) v = *(const float4*)(S + ((size_t)n * BS + b) * C + k);
    _Float16 h[4] = {(_Float16)v.x, (_Float16)v.y, (_Float16)v.z, (_Float16)v.w};
    *(uint2*)(sh + idx) = *(uint2*)h;
}

// ---------------- single-pass fp16 MFMA GEMM (512 threads, BK=64, XCD-gathered, NT) ----------------
// sim[b][n][k] = sum_c S[n][b][c] * Q[k][b][c]
// 8 waves/block, each owns 32 hw rows -> acc[2][7] = 56 AGPR -> 4 waves/SIMD
// (16 waves/CU) for 2x latency hiding. Tile/burst geometry unchanged from the
// R14/R15 champion (BM=256, BK=64, XCD-gather dispatch, NT sim stores).
template<bool USE_WS>
__global__ __launch_bounds__(512, 4) void gemm_kernel(const float* __restrict__ Q,
                                                      const float* __restrict__ S,
                                                      const _Float16* __restrict__ ShG,
                                                      float* __restrict__ out,
                                                      float* __restrict__ pm,
                                                      float* __restrict__ pz,
                                                      float* __restrict__ pwx,
                                                      float* __restrict__ pwy,
                                                      int* __restrict__ pidx)
{
    // Qf: 256 rows x 64 f32 (256 B row, 16 chunks). chunk c at slot c ^ (row&15). 64 KB
    __shared__ __align__(16) float    Qf[BM * BK];
    // SH: 112 rows x 64 f16 (128 B row, 8 chunks). chunk c at slot c ^ (row&7).  14 KB
    __shared__ __align__(16) _Float16 SH[NQP * BK];
    // Ws (epilogue partials, [NQP][8][4] floats = 14336 B) reuses SH after the K loop.

    // ---- XCD-gather decode: id = c + 8*(b + 16*xhi); x = 8*xhi + c ----
    const int id  = blockIdx.x;
    const int xc  = id & 7;
    const int m_  = id >> 3;
    const int b   = m_ & 15;
    const int x   = ((m_ >> 4) << 3) | xc;
    const int hw0 = x * BM;

    const int t    = threadIdx.x;
    const int wid  = t >> 6;       // 0..7, owns hw rows wid*32..wid*32+31
    const int lane = t & 63;
    const int lr   = lane & 15;    // A-row / B-col within fragment
    const int lg   = lane >> 4;    // k-group (0..3)

    // acc[am][bn]: hw = wid*32 + 16*am + 4*lg + j, nq = 16*bn + lr
    f32x4 acc[2][7];
    #pragma unroll
    for (int am = 0; am < 2; ++am)
        #pragma unroll
        for (int bn = 0; bn < 7; ++bn)
            acc[am][bn] = (f32x4)(0.f);

    // staging lane decomposition
    const int q_ri = lane >> 4;                       // row within 4-row group (Q)
    const int s_ri = lane >> 3;                       // row within 8-row group (S)
    const int s_gc = (lane & 7) ^ s_ri;               // pre-swizzled S chunk (f16 x8)

    for (int k0 = 0; k0 < C; k0 += BK) {
        // ---- stage Q tile: 8 gll16/wave, 4 rows x 256 B each (wave-private rows) ----
        #pragma unroll
        for (int p = 0; p < 8; ++p) {
            int rt  = wid * 32 + p * 4;
            int r15 = (p * 4 + q_ri) & 15;
            int gc  = (lane & 15) ^ r15;
            const float* g = Q + ((size_t)(hw0 + rt + q_ri) * BS + b) * C + k0 + gc * 4;
            gll16(g, &Qf[rt * BK]);
        }
        // ---- stage S fp16 tile (14 gll16 spread over 8 waves) ----
        if (USE_WS) {
            for (int i = wid; i < 14; i += NW) {
                int r0 = i * 8;
                const _Float16* g = ShG + ((size_t)b * NQP + r0 + s_ri) * C + k0 + s_gc * 8;
                gll16(g, &SH[r0 * BK]);
            }
        }
        __syncthreads();

        // ---- 2 MFMA sub-steps of K=32 ----
        #pragma unroll
        for (int s = 0; s < 2; ++s) {
            half8 qh[2];
            #pragma unroll
            for (int am = 0; am < 2; ++am) {
                int row = wid * 32 + 16 * am + lr;
                int c0  = 8 * s + 2 * lg;
                int r15 = row & 15;
                float4 qa = *(const float4*)&Qf[row * BK + (((c0)     ^ r15) << 2)];
                float4 qb = *(const float4*)&Qf[row * BK + (((c0 + 1) ^ r15) << 2)];
                qh[am] = cvt8(qa, qb);
            }
            #pragma unroll
            for (int bn = 0; bn < 7; ++bn) {
                int row = 16 * bn + lr;
                half8 sh;
                if (USE_WS) {
                    int sl = (4 * s + lg) ^ (row & 7);
                    sh = *(const half8*)&SH[row * BK + sl * 8];
                } else {
                    if (row < NQ) {
                        const float* g = S + ((size_t)row * BS + b) * C + k0 + 32 * s + 8 * lg;
                        float4 sa = *(const float4*)g;
                        float4 sb = *(const float4*)(g + 4);
                        sh = cvt8(sa, sb);
                    } else {
                        sh = (half8)(_Float16)0.f;
                    }
                }
                #pragma unroll
                for (int am = 0; am < 2; ++am)
                    acc[am][bn] = __builtin_amdgcn_mfma_f32_16x16x32_f16(qh[am], sh, acc[am][bn], 0, 0, 0);
            }
        }
        __syncthreads();
    }

    // ---- epilogue: sim store (NT dwordx4) + per-row stats (lane-local) ----
    float* Ws = (float*)&SH[0];                    // [NQP][8][4] floats (reuse, 14336 B)

    float* simb = out + SIM_OFF;
    const int hwl0 = wid * 32 + 4 * lg;            // local hw base (0..255)
    #pragma unroll
    for (int bn = 0; bn < 7; ++bn) {
        int nq = 16 * bn + lr;
        if (nq < NQ) {
            size_t rbase = ((size_t)(b * NQ + nq)) * HW + hw0 + hwl0;
            #pragma unroll
            for (int am = 0; am < 2; ++am)
                __builtin_nontemporal_store(acc[am][bn], (f32x4*)&simb[rbase + 16 * am]);
        }
        if (USE_WS) {
            // per-thread max/argmax over 8 register values (ascending local idx,
            // strict > -> lowest idx wins ties)
            float vm = acc[0][bn][0];
            int   ci = hwl0;
            #pragma unroll
            for (int am = 0; am < 2; ++am)
                #pragma unroll
                for (int j = 0; j < 4; ++j) {
                    float v = acc[am][bn][j];
                    if (v > vm) { vm = v; ci = hwl0 + 16 * am + j; }
                }
            float z = 0.f, wx = 0.f;
            #pragma unroll
            for (int am = 0; am < 2; ++am)
                #pragma unroll
                for (int j = 0; j < 4; ++j) {
                    float e = __expf(acc[am][bn][j] - vm);
                    z += e;
                    wx += e * ((float)((hwl0 + 16 * am + j) & 127) + 0.5f);
                }
            // 2-step ladder over the 4 lg-lanes holding this nq (xor 16, 32)
            #pragma unroll
            for (int off = 16; off < 64; off <<= 1) {
                float om = __shfl_xor(vm, off);
                int   oc = __shfl_xor(ci, off);
                float oz = __shfl_xor(z, off);
                float ox = __shfl_xor(wx, off);
                bool take = (om > vm) || (om == vm && oc < ci);
                float mn = take ? om : vm;
                float ss = __expf(vm - mn);
                float so = __expf(om - mn);
                z  = z * ss + oz * so;
                wx = wx * ss + ox * so;
                vm = mn;
                ci = take ? oc : ci;
            }
            if (lg == 0) {
                f32x4 tu = {vm, __int_as_float(ci), z, wx};
                *(f32x4*)&Ws[(nq * NW + wid) * 4] = tu;
            }
        }
    }
    if (USE_WS) {
        __syncthreads();
        if (t < NQ) {
            int nq = t;
            float M = -3.4e38f; int gi = 0;
            float mw[NW], zw[NW], xw[NW]; int cw[NW];
            #pragma unroll
            for (int w = 0; w < NW; ++w) {
                f32x4 tu = *(const f32x4*)&Ws[(nq * NW + w) * 4];
                mw[w] = tu[0]; cw[w] = __float_as_int(tu[1]); zw[w] = tu[2]; xw[w] = tu[3];
                if (mw[w] > M || (mw[w] == M && cw[w] < gi)) { M = mw[w]; gi = cw[w]; }
            }
            float ybase = (float)(hw0 >> 7) + 0.5f;
            float Zp = 0.f, WXp = 0.f, WYp = 0.f;
            #pragma unroll
            for (int w = 0; w < NW; ++w) {
                float s = __expf(mw[w] - M);
                Zp  += zw[w] * s;
                WXp += xw[w] * s;
                WYp += zw[w] * s * (ybase + (float)(w >> 2));   // y uniform per wave (rows wid*32..+31)
            }
            size_t pbase = ((size_t)b * NBLK + x) * NQ + nq;
            pm[pbase] = M; pz[pbase] = Zp; pwx[pbase] = WXp; pwy[pbase] = WYp;
            pidx[pbase] = hw0 + gi;
        }
    }
}

// ---------------- finalize: combine 64 partials per row ----------------
__global__ __launch_bounds__(256) void finalize_kernel(const float* __restrict__ sim,
                                                       const float* __restrict__ pm,
                                                       const float* __restrict__ pz,
                                                       const float* __restrict__ pwx,
                                                       const float* __restrict__ pwy,
                                                       const int* __restrict__ pidx,
                                                       float* __restrict__ out)
{
    const int rglob = blockIdx.x * 4 + (threadIdx.x >> 6);  // 0..1599 = b*NQ + n
    const int lane  = threadIdx.x & 63;                     // = partial block id
    const int b     = rglob / NQ;
    const int n     = rglob - b * NQ;
    const size_t base = ((size_t)b * NBLK + lane) * NQ + n;

    float m  = pm[base];
    float z  = pz[base];
    float wx = pwx[base];
    float wy = pwy[base];
    int   gi = pidx[base];

    float v = m; int vi = gi;
    #pragma unroll
    for (int off = 1; off < 64; off <<= 1) {
        float ov = __shfl_xor(v, off);
        int   oi = __shfl_xor(vi, off);
        if (ov > v || (ov == v && oi < vi)) { v = ov; vi = oi; }
    }
    float s  = __expf(m - v);
    float Z  = z * s;
    float WX = wx * s;
    float WY = wy * s;
    #pragma unroll
    for (int off = 1; off < 64; off <<= 1) {
        Z  += __shfl_xor(Z, off);
        WX += __shfl_xor(WX, off);
        WY += __shfl_xor(WY, off);
    }
    if (lane == 0) {
        out[(size_t)rglob * 2 + 0] = (WX / Z) * (1.f / 128.f);
        out[(size_t)rglob * 2 + 1] = (WY / Z) * (1.f / 128.f);
        const float* srow = sim + (size_t)rglob * HW;
        int pr = vi >> 7, pc = vi & 127;
        float ls = 0.f, lx = 0.f, ly = 0.f;
        #pragma unroll
        for (int dr = -1; dr <= 1; ++dr) {
            #pragma unroll
            for (int dc = -1; dc <= 1; ++dc) {
                int r = pr + dr, c = pc + dc;
                if (r >= 0 && r < Ww && c >= 0 && c < Hh) {
                    int k = r * Hh + c;
                    float e = __expf(srow[k] - v);
                    ls += e;
                    lx += e * ((float)(k & 127) + 0.5f);
                    ly += e * ((float)(k >> 7) + 0.5f);
                }
            }
        }
        float denom = ls + 1e-10f * Z;
        out[PROPS_OFF + (size_t)rglob * 2 + 0] = (lx / denom) * (1.f / 128.f);
        out[PROPS_OFF + (size_t)rglob * 2 + 1] = (ly / denom) * (1.f / 128.f);
    }
}

// ---------------- fallback row-reduction kernel (no-ws path) ----------------
__global__ __launch_bounds__(256) void reduce_kernel(const float* __restrict__ sim,
                                                     float* __restrict__ out)
{
    __shared__ float rowbuf[HW];
    __shared__ float s_pm[4];
    __shared__ int   s_pi[4];
    __shared__ float s_red[4][3];
    __shared__ float s_gmax;
    __shared__ int   s_gidx;

    const int row = blockIdx.x;
    const int t   = threadIdx.x;
    const int wid  = t >> 6;
    const int lane = t & 63;
    const float4* src4 = (const float4*)(sim + (size_t)row * HW);

    float vmax = -3.4e38f;
    int   vidx = 0;
    #pragma unroll
    for (int p = 0; p < 16; ++p) {
        int i4 = p * 256 + t;
        float4 v = src4[i4];
        *(float4*)&rowbuf[i4 * 4] = v;
        int base = i4 * 4;
        if (v.x > vmax) { vmax = v.x; vidx = base; }
        if (v.y > vmax) { vmax = v.y; vidx = base + 1; }
        if (v.z > vmax) { vmax = v.z; vidx = base + 2; }
        if (v.w > vmax) { vmax = v.w; vidx = base + 3; }
    }
    #pragma unroll
    for (int off = 32; off > 0; off >>= 1) {
        float ov = __shfl_down(vmax, off);
        int   oi = __shfl_down(vidx, off);
        if (ov > vmax || (ov == vmax && oi < vidx)) { vmax = ov; vidx = oi; }
    }
    if (lane == 0) { s_pm[wid] = vmax; s_pi[wid] = vidx; }
    __syncthreads();
    if (t == 0) {
        float gm = s_pm[0]; int gi = s_pi[0];
        #pragma unroll
        for (int wv = 1; wv < 4; ++wv) {
            float ov = s_pm[wv]; int oi = s_pi[wv];
            if (ov > gm || (ov == gm && oi < gi)) { gm = ov; gi = oi; }
        }
        s_gmax = gm; s_gidx = gi;
    }
    __syncthreads();
    const float gmax = s_gmax;

    float z = 0.f, wx = 0.f, wy = 0.f;
    #pragma unroll
    for (int p = 0; p < 16; ++p) {
        int i4 = p * 256 + t;
        float4 v = *(const float4*)&rowbuf[i4 * 4];
        int i = i4 * 4;
        float e0 = __expf(v.x - gmax), e1 = __expf(v.y - gmax);
        float e2 = __expf(v.z - gmax), e3 = __expf(v.w - gmax);
        z += (e0 + e1) + (e2 + e3);
        float cy = (float)(i >> 7) + 0.5f;
        float cx0 = (float)(i & (Ww - 1)) + 0.5f;
        wx += e0 * cx0 + e1 * (cx0 + 1.f) + e2 * (cx0 + 2.f) + e3 * (cx0 + 3.f);
        wy += (e0 + e1 + e2 + e3) * cy;
    }
    #pragma unroll
    for (int off = 32; off > 0; off >>= 1) {
        z  += __shfl_down(z, off);
        wx += __shfl_down(wx, off);
        wy += __shfl_down(wy, off);
    }
    if (lane == 0) { s_red[wid][0] = z; s_red[wid][1] = wx; s_red[wid][2] = wy; }
    __syncthreads();

    if (t == 0) {
        float Z = 0.f, WX = 0.f, WY = 0.f;
        #pragma unroll
        for (int wv = 0; wv < 4; ++wv) { Z += s_red[wv][0]; WX += s_red[wv][1]; WY += s_red[wv][2]; }

        out[(size_t)row * 2 + 0] = (WX / Z) * (1.0f / (float)Ww);
        out[(size_t)row * 2 + 1] = (WY / Z) * (1.0f / (float)Hh);

        int p  = s_gidx;
        int pr = p / Hh;
        int pc = p % Hh;
        float lsum = 0.f, lwx = 0.f, lwy = 0.f;
        #pragma unroll
        for (int di = -1; di <= 1; ++di) {
            #pragma unroll
            for (int dj = -1; dj <= 1; ++dj) {
                int r = pr + di, c = pc + dj;
                if (r >= 0 && r < Ww && c >= 0 && c < Hh) {
                    int k = r * Hh + c;
                    float e = __expf(rowbuf[k] - gmax);
                    lsum += e;
                    lwx  += e * ((float)(k & (Ww - 1)) + 0.5f);
                    lwy  += e * ((float)(k >> 7) + 0.5f);
                }
            }
        }
        float denom = lsum + 1e-10f * Z;
        out[PROPS_OFF + (size_t)row * 2 + 0] = (lwx / denom) * (1.0f / (float)Ww);
        out[PROPS_OFF + (size_t)row * 2 + 1] = (lwy / denom) * (1.0f / (float)Hh);
    }
}

extern "C" void kernel_launch(void* const* d_in, const int* in_sizes, int n_in,
                              void* d_out, int out_size, void* d_ws, size_t ws_size,
                              hipStream_t stream) {
    const float* Q = (const float*)d_in[0];   // [hw, bs, c]
    const float* S = (const float*)d_in[1];   // [nq, bs, c]
    float* out = (float*)d_out;

    const size_t splitElems = (size_t)BS * NQP * C;            // 458752 halves
    const size_t splitBytes = splitElems * sizeof(_Float16);
    const size_t nPart = (size_t)BS * NQ * NBLK;               // 102400
    const size_t pOff  = (splitBytes + 255) & ~(size_t)255;
    const size_t wsNeeded = pOff + nPart * 5 * sizeof(float);

    if (ws_size >= wsNeeded) {
        _Float16* sh = (_Float16*)d_ws;
        float* pm  = (float*)((char*)d_ws + pOff);
        float* pz  = pm + nPart;
        float* pwx = pz + nPart;
        float* pwy = pwx + nPart;
        int*   pidx = (int*)(pwy + nPart);
        conv_S_kernel<<<dim3((unsigned)((splitElems / 4 + 255) / 256)), 256, 0, stream>>>(S, sh);
        gemm_kernel<true><<<dim3(HW / BM * BS), 512, 0, stream>>>(Q, S, sh, out,
                                                                  pm, pz, pwx, pwy, pidx);
        finalize_kernel<<<dim3(BS * NQ / 4), 256, 0, stream>>>(out + SIM_OFF, pm, pz, pwx, pwy, pidx, out);
    } else {
        gemm_kernel<false><<<dim3(HW / BM * BS), 512, 0, stream>>>(Q, S, nullptr, out,
                                                                   nullptr, nullptr, nullptr, nullptr, nullptr);
        reduce_kernel<<<dim3(BS * NQ), 256, 0, stream>>>(out + SIM_OFF, out);
    }
}

// Round 17
// 95.689 us; speedup vs baseline: 1.0933x; 1.0933x over previous
//
#include <hip/hip_runtime.h>
#include <math.h>

// Problem dims (fixed by setup_inputs)
#define HW   16384
#define BS   16
#define C    256
#define NQ   100
#define NQP  112          // padded nq (7 x 16)
#define Hh   128
#define Ww   128

// output layout offsets (floats)
#define SIM_OFF   3200                 // after proposal_for_loss [16,100,2]
#define PROPS_OFF (3200 + 26214400)    // after similarity [16,100,16384]

#define BM 256           // hw per block (2 grid rows)
#define BK 64            // k per step (2 MFMA sub-steps of K=32)
#define NBLK (HW / BM)   // 64 partials per row

typedef _Float16 half8 __attribute__((ext_vector_type(8)));
typedef float f32x4 __attribute__((ext_vector_type(4)));

__device__ __forceinline__ void gll16(const void* gp, void* lp) {
    __builtin_amdgcn_global_load_lds((const __attribute__((address_space(1))) void*)gp,
                                     (__attribute__((address_space(3))) void*)lp, 16, 0, 0);
}

__device__ __forceinline__ half8 cvt8(const float4 a, const float4 b) {
    _Float16 h[8] = {(_Float16)a.x, (_Float16)a.y, (_Float16)a.z, (_Float16)a.w,
                     (_Float16)b.x, (_Float16)b.y, (_Float16)b.z, (_Float16)b.w};
    return *(half8*)h;
}

// ---------------- S pre-convert kernel ----------------
// S [nq, bs, c] fp32 -> Sh [bs][112][256] fp16 (rows >= NQ zero)
__global__ __launch_bounds__(256) void conv_S_kernel(const float* __restrict__ S,
                                                     _Float16* __restrict__ sh)
{
    int idx4 = blockIdx.x * 256 + threadIdx.x;
    int idx = idx4 * 4;
    if (idx >= BS * NQP * C) return;
    int b = idx / (NQP * C);
    int rem = idx - b * (NQP * C);
    int n = rem / C;
    int k = rem - n * C;
    float4 v = make_float4(0.f, 0.f, 0.f, 0.f);
    if (n < NQ) v = *(const float4*)(S + ((size_t)n * BS + b) * C + k);
    _Float16 h[4] = {(_Float16)v.x, (_Float16)v.y, (_Float16)v.z, (_Float16)v.w};
    *(uint2*)(sh + idx) = *(uint2*)h;
}

// ---------------- single-pass fp16 MFMA GEMM (BK=64, XCD-gathered, NT sim store) ----------------
// sim[b][n][k] = sum_c S[n][b][c] * Q[k][b][c]
// A = Q (hw), B = S (nq). Dispatch swizzle: id = c + 8*(b + 16*xhi) puts the
// 16 batch-variants of one hw-strip on ONE XCD back-to-back.
// sim stores are NON-TEMPORAL: output written once, never re-read hot ->
// keep it out of L2/L3 so Q stays L3-resident across graph replays.
template<bool USE_WS>
__global__ __launch_bounds__(256, 2) void gemm_kernel(const float* __restrict__ Q,
                                                      const float* __restrict__ S,
                                                      const _Float16* __restrict__ ShG,
                                                      float* __restrict__ out,
                                                      float* __restrict__ pm,
                                                      float* __restrict__ pz,
                                                      float* __restrict__ pwx,
                                                      float* __restrict__ pwy,
                                                      int* __restrict__ pidx)
{
    // Qf: 256 rows x 64 f32 (256 B row, 16 chunks). chunk c at slot c ^ (row&15). 64 KB
    __shared__ __align__(16) float    Qf[BM * BK];
    // SH: 112 rows x 64 f16 (128 B row, 8 chunks). chunk c at slot c ^ (row&7).  14 KB
    __shared__ __align__(16) _Float16 SH[NQP * BK];
    // Ws (epilogue partials) reuses SH after the K loop.

    // ---- XCD-gather decode: id = c + 8*(b + 16*xhi); x = 8*xhi + c ----
    const int id  = blockIdx.x;
    const int xc  = id & 7;
    const int m_  = id >> 3;
    const int b   = m_ & 15;
    const int x   = ((m_ >> 4) << 3) | xc;
    const int hw0 = x * BM;

    const int t    = threadIdx.x;
    const int wid  = t >> 6;
    const int lane = t & 63;
    const int lr   = lane & 15;    // A-row / B-col within fragment
    const int lg   = lane >> 4;    // k-group (0..3)

    // acc[am][bn]: hw = wid*64 + 16*am + 4*lg + j, nq = 16*bn + lr
    f32x4 acc[4][7];
    #pragma unroll
    for (int am = 0; am < 4; ++am)
        #pragma unroll
        for (int bn = 0; bn < 7; ++bn)
            acc[am][bn] = (f32x4)(0.f);

    // staging lane decomposition
    const int q_ri = lane >> 4;                       // row within 4-row group (Q)
    const int s_ri = lane >> 3;                       // row within 8-row group (S)
    const int s_gc = (lane & 7) ^ s_ri;               // pre-swizzled S chunk (f16 x8)

    for (int k0 = 0; k0 < C; k0 += BK) {
        // ---- stage Q tile: 16 gll16/wave, 4 rows x 256 B each, pre-swizzled source ----
        #pragma unroll
        for (int p = 0; p < 16; ++p) {
            int rt  = wid * 64 + p * 4;
            int r15 = (p * 4 + q_ri) & 15;
            int gc  = (lane & 15) ^ r15;
            const float* g = Q + ((size_t)(hw0 + rt + q_ri) * BS + b) * C + k0 + gc * 4;
            gll16(g, &Qf[rt * BK]);
        }
        // ---- stage S fp16 tile (14 gll16 spread over waves) ----
        if (USE_WS) {
            for (int i = wid; i < 14; i += 4) {
                int r0 = i * 8;
                const _Float16* g = ShG + ((size_t)b * NQP + r0 + s_ri) * C + k0 + s_gc * 8;
                gll16(g, &SH[r0 * BK]);
            }
        }
        __syncthreads();

        // ---- 2 MFMA sub-steps of K=32 ----
        #pragma unroll
        for (int s = 0; s < 2; ++s) {
            half8 qh[4];
            #pragma unroll
            for (int am = 0; am < 4; ++am) {
                int row = wid * 64 + 16 * am + lr;
                int c0  = 8 * s + 2 * lg;
                float4 qa = *(const float4*)&Qf[row * BK + (((c0)     ^ lr) << 2)];
                float4 qb = *(const float4*)&Qf[row * BK + (((c0 + 1) ^ lr) << 2)];
                qh[am] = cvt8(qa, qb);
            }
            #pragma unroll
            for (int bn = 0; bn < 7; ++bn) {
                int row = 16 * bn + lr;
                half8 sh;
                if (USE_WS) {
                    int sl = (4 * s + lg) ^ (row & 7);
                    sh = *(const half8*)&SH[row * BK + sl * 8];
                } else {
                    if (row < NQ) {
                        const float* g = S + ((size_t)row * BS + b) * C + k0 + 32 * s + 8 * lg;
                        float4 sa = *(const float4*)g;
                        float4 sb = *(const float4*)(g + 4);
                        sh = cvt8(sa, sb);
                    } else {
                        sh = (half8)(_Float16)0.f;
                    }
                }
                #pragma unroll
                for (int am = 0; am < 4; ++am)
                    acc[am][bn] = __builtin_amdgcn_mfma_f32_16x16x32_f16(qh[am], sh, acc[am][bn], 0, 0, 0);
            }
        }
        __syncthreads();
    }

    // ---- epilogue: sim store (NT dwordx4) + per-row stats (lane-local) ----
    float* Ws = (float*)&SH[0];                    // [NQP][4][4] floats (reuse)

    float* simb = out + SIM_OFF;
    const int hwl0 = wid * 64 + 4 * lg;            // local hw base (0..255)
    #pragma unroll
    for (int bn = 0; bn < 7; ++bn) {
        int nq = 16 * bn + lr;
        if (nq < NQ) {
            size_t rbase = ((size_t)(b * NQ + nq)) * HW + hw0 + hwl0;
            #pragma unroll
            for (int am = 0; am < 4; ++am)
                __builtin_nontemporal_store(acc[am][bn], (f32x4*)&simb[rbase + 16 * am]);
        }
        if (USE_WS) {
            // per-thread max/argmax over 16 register values (ascending local idx,
            // strict > -> lowest idx wins ties)
            float vm = acc[0][bn][0];
            int   ci = hwl0;
            #pragma unroll
            for (int am = 0; am < 4; ++am)
                #pragma unroll
                for (int j = 0; j < 4; ++j) {
                    float v = acc[am][bn][j];
                    if (v > vm) { vm = v; ci = hwl0 + 16 * am + j; }
                }
            float z = 0.f, wx = 0.f;
            #pragma unroll
            for (int am = 0; am < 4; ++am)
                #pragma unroll
                for (int j = 0; j < 4; ++j) {
                    float e = __expf(acc[am][bn][j] - vm);
                    z += e;
                    wx += e * ((float)((hwl0 + 16 * am + j) & 127) + 0.5f);
                }
            // 2-step ladder over the 4 lg-lanes holding this nq (xor 16, 32)
            #pragma unroll
            for (int off = 16; off < 64; off <<= 1) {
                float om = __shfl_xor(vm, off);
                int   oc = __shfl_xor(ci, off);
                float oz = __shfl_xor(z, off);
                float ox = __shfl_xor(wx, off);
                bool take = (om > vm) || (om == vm && oc < ci);
                float mn = take ? om : vm;
                float ss = __expf(vm - mn);
                float so = __expf(om - mn);
                z  = z * ss + oz * so;
                wx = wx * ss + ox * so;
                vm = mn;
                ci = take ? oc : ci;
            }
            if (lg == 0) {
                f32x4 tu = {vm, __int_as_float(ci), z, wx};
                *(f32x4*)&Ws[(nq * 4 + wid) * 4] = tu;
            }
        }
    }
    if (USE_WS) {
        __syncthreads();
        if (t < NQ) {
            int nq = t;
            float M = -3.4e38f; int gi = 0;
            float mw[4], zw[4], xw[4]; int cw[4];
            #pragma unroll
            for (int w = 0; w < 4; ++w) {
                f32x4 tu = *(const f32x4*)&Ws[(nq * 4 + w) * 4];
                mw[w] = tu[0]; cw[w] = __float_as_int(tu[1]); zw[w] = tu[2]; xw[w] = tu[3];
                if (mw[w] > M || (mw[w] == M && cw[w] < gi)) { M = mw[w]; gi = cw[w]; }
            }
            float ybase = (float)(hw0 >> 7) + 0.5f;
            float Zp = 0.f, WXp = 0.f, WYp = 0.f;
            #pragma unroll
            for (int w = 0; w < 4; ++w) {
                float s = __expf(mw[w] - M);
                Zp  += zw[w] * s;
                WXp += xw[w] * s;
                WYp += zw[w] * s * (ybase + (float)(w >> 1));   // y uniform per wid
            }
            size_t pbase = ((size_t)b * NBLK + x) * NQ + nq;
            pm[pbase] = M; pz[pbase] = Zp; pwx[pbase] = WXp; pwy[pbase] = WYp;
            pidx[pbase] = hw0 + gi;
        }
    }
}

// ---------------- finalize: combine 64 partials per row ----------------
__global__ __launch_bounds__(256) void finalize_kernel(const float* __restrict__ sim,
                                                       const float* __restrict__ pm,
                                                       const float* __restrict__ pz,
                                                       const float* __restrict__ pwx,
                                                       const float* __restrict__ pwy,
                                                       const int* __restrict__ pidx,
                                                       float* __restrict__ out)
{
    const int rglob = blockIdx.x * 4 + (threadIdx.x >> 6);  // 0..1599 = b*NQ + n
    const int lane  = threadIdx.x & 63;                     // = partial block id
    const int b     = rglob / NQ;
    const int n     = rglob - b * NQ;
    const size_t base = ((size_t)b * NBLK + lane) * NQ + n;

    float m  = pm[base];
    float z  = pz[base];
    float wx = pwx[base];
    float wy = pwy[base];
    int   gi = pidx[base];

    float v = m; int vi = gi;
    #pragma unroll
    for (int off = 1; off < 64; off <<= 1) {
        float ov = __shfl_xor(v, off);
        int   oi = __shfl_xor(vi, off);
        if (ov > v || (ov == v && oi < vi)) { v = ov; vi = oi; }
    }
    float s  = __expf(m - v);
    float Z  = z * s;
    float WX = wx * s;
    float WY = wy * s;
    #pragma unroll
    for (int off = 1; off < 64; off <<= 1) {
        Z  += __shfl_xor(Z, off);
        WX += __shfl_xor(WX, off);
        WY += __shfl_xor(WY, off);
    }
    if (lane == 0) {
        out[(size_t)rglob * 2 + 0] = (WX / Z) * (1.f / 128.f);
        out[(size_t)rglob * 2 + 1] = (WY / Z) * (1.f / 128.f);
        const float* srow = sim + (size_t)rglob * HW;
        int pr = vi >> 7, pc = vi & 127;
        float ls = 0.f, lx = 0.f, ly = 0.f;
        #pragma unroll
        for (int dr = -1; dr <= 1; ++dr) {
            #pragma unroll
            for (int dc = -1; dc <= 1; ++dc) {
                int r = pr + dr, c = pc + dc;
                if (r >= 0 && r < Ww && c >= 0 && c < Hh) {
                    int k = r * Hh + c;
                    float e = __expf(srow[k] - v);
                    ls += e;
                    lx += e * ((float)(k & 127) + 0.5f);
                    ly += e * ((float)(k >> 7) + 0.5f);
                }
            }
        }
        float denom = ls + 1e-10f * Z;
        out[PROPS_OFF + (size_t)rglob * 2 + 0] = (lx / denom) * (1.f / 128.f);
        out[PROPS_OFF + (size_t)rglob * 2 + 1] = (ly / denom) * (1.f / 128.f);
    }
}

// ---------------- fallback row-reduction kernel (no-ws path) ----------------
__global__ __launch_bounds__(256) void reduce_kernel(const float* __restrict__ sim,
                                                     float* __restrict__ out)
{
    __shared__ float rowbuf[HW];
    __shared__ float s_pm[4];
    __shared__ int   s_pi[4];
    __shared__ float s_red[4][3];
    __shared__ float s_gmax;
    __shared__ int   s_gidx;

    const int row = blockIdx.x;
    const int t   = threadIdx.x;
    const int wid  = t >> 6;
    const int lane = t & 63;
    const float4* src4 = (const float4*)(sim + (size_t)row * HW);

    float vmax = -3.4e38f;
    int   vidx = 0;
    #pragma unroll
    for (int p = 0; p < 16; ++p) {
        int i4 = p * 256 + t;
        float4 v = src4[i4];
        *(float4*)&rowbuf[i4 * 4] = v;
        int base = i4 * 4;
        if (v.x > vmax) { vmax = v.x; vidx = base; }
        if (v.y > vmax) { vmax = v.y; vidx = base + 1; }
        if (v.z > vmax) { vmax = v.z; vidx = base + 2; }
        if (v.w > vmax) { vmax = v.w; vidx = base + 3; }
    }
    #pragma unroll
    for (int off = 32; off > 0; off >>= 1) {
        float ov = __shfl_down(vmax, off);
        int   oi = __shfl_down(vidx, off);
        if (ov > vmax || (ov == vmax && oi < vidx)) { vmax = ov; vidx = oi; }
    }
    if (lane == 0) { s_pm[wid] = vmax; s_pi[wid] = vidx; }
    __syncthreads();
    if (t == 0) {
        float gm = s_pm[0]; int gi = s_pi[0];
        #pragma unroll
        for (int wv = 1; wv < 4; ++wv) {
            float ov = s_pm[wv]; int oi = s_pi[wv];
            if (ov > gm || (ov == gm && oi < gi)) { gm = ov; gi = oi; }
        }
        s_gmax = gm; s_gidx = gi;
    }
    __syncthreads();
    const float gmax = s_gmax;

    float z = 0.f, wx = 0.f, wy = 0.f;
    #pragma unroll
    for (int p = 0; p < 16; ++p) {
        int i4 = p * 256 + t;
        float4 v = *(const float4*)&rowbuf[i4 * 4];
        int i = i4 * 4;
        float e0 = __expf(v.x - gmax), e1 = __expf(v.y - gmax);
        float e2 = __expf(v.z - gmax), e3 = __expf(v.w - gmax);
        z += (e0 + e1) + (e2 + e3);
        float cy = (float)(i >> 7) + 0.5f;
        float cx0 = (float)(i & (Ww - 1)) + 0.5f;
        wx += e0 * cx0 + e1 * (cx0 + 1.f) + e2 * (cx0 + 2.f) + e3 * (cx0 + 3.f);
        wy += (e0 + e1 + e2 + e3) * cy;
    }
    #pragma unroll
    for (int off = 32; off > 0; off >>= 1) {
        z  += __shfl_down(z, off);
        wx += __shfl_down(wx, off);
        wy += __shfl_down(wy, off);
    }
    if (lane == 0) { s_red[wid][0] = z; s_red[wid][1] = wx; s_red[wid][2] = wy; }
    __syncthreads();

    if (t == 0) {
        float Z = 0.f, WX = 0.f, WY = 0.f;
        #pragma unroll
        for (int wv = 0; wv < 4; ++wv) { Z += s_red[wv][0]; WX += s_red[wv][1]; WY += s_red[wv][2]; }

        out[(size_t)row * 2 + 0] = (WX / Z) * (1.0f / (float)Ww);
        out[(size_t)row * 2 + 1] = (WY / Z) * (1.0f / (float)Hh);

        int p  = s_gidx;
        int pr = p / Hh;
        int pc = p % Hh;
        float lsum = 0.f, lwx = 0.f, lwy = 0.f;
        #pragma unroll
        for (int di = -1; di <= 1; ++di) {
            #pragma unroll
            for (int dj = -1; dj <= 1; ++dj) {
                int r = pr + di, c = pc + dj;
                if (r >= 0 && r < Ww && c >= 0 && c < Hh) {
                    int k = r * Hh + c;
                    float e = __expf(rowbuf[k] - gmax);
                    lsum += e;
                    lwx  += e * ((float)(k & (Ww - 1)) + 0.5f);
                    lwy  += e * ((float)(k >> 7) + 0.5f);
                }
            }
        }
        float denom = lsum + 1e-10f * Z;
        out[PROPS_OFF + (size_t)row * 2 + 0] = (lwx / denom) * (1.0f / (float)Ww);
        out[PROPS_OFF + (size_t)row * 2 + 1] = (lwy / denom) * (1.0f / (float)Hh);
    }
}

extern "C" void kernel_launch(void* const* d_in, const int* in_sizes, int n_in,
                              void* d_out, int out_size, void* d_ws, size_t ws_size,
                              hipStream_t stream) {
    const float* Q = (const float*)d_in[0];   // [hw, bs, c]
    const float* S = (const float*)d_in[1];   // [nq, bs, c]
    float* out = (float*)d_out;

    const size_t splitElems = (size_t)BS * NQP * C;            // 458752 halves
    const size_t splitBytes = splitElems * sizeof(_Float16);
    const size_t nPart = (size_t)BS * NQ * NBLK;               // 102400
    const size_t pOff  = (splitBytes + 255) & ~(size_t)255;
    const size_t wsNeeded = pOff + nPart * 5 * sizeof(float);

    if (ws_size >= wsNeeded) {
        _Float16* sh = (_Float16*)d_ws;
        float* pm  = (float*)((char*)d_ws + pOff);
        float* pz  = pm + nPart;
        float* pwx = pz + nPart;
        float* pwy = pwx + nPart;
        int*   pidx = (int*)(pwy + nPart);
        conv_S_kernel<<<dim3((unsigned)((splitElems / 4 + 255) / 256)), 256, 0, stream>>>(S, sh);
        gemm_kernel<true><<<dim3(HW / BM * BS), 256, 0, stream>>>(Q, S, sh, out,
                                                                  pm, pz, pwx, pwy, pidx);
        finalize_kernel<<<dim3(BS * NQ / 4), 256, 0, stream>>>(out + SIM_OFF, pm, pz, pwx, pwy, pidx, out);
    } else {
        gemm_kernel<false><<<dim3(HW / BM * BS), 256, 0, stream>>>(Q, S, nullptr, out,
                                                                   nullptr, nullptr, nullptr, nullptr, nullptr);
        reduce_kernel<<<dim3(BS * NQ), 256, 0, stream>>>(out + SIM_OFF, out);
    }
}